// Round 12
// baseline (17504.263 us; speedup 1.0000x reference)
//
#include <hip/hip_runtime.h>

#define H 1024
#define V 32000
#define STEPS 375
#define NB1 256     // gru/tail blocks
#define NB2 512     // logits blocks
#define RPB1 125    // out cols per gru block

__device__ __forceinline__ float dot4(const float4 a, const float4 b) {
    return fmaf(a.x, b.x, fmaf(a.y, b.y, fmaf(a.z, b.z, a.w * b.w)));
}

__device__ __forceinline__ float wave_sum(float v) {
#pragma unroll
    for (int off = 32; off > 0; off >>= 1) v += __shfl_xor(v, off);
    return v;
}

__device__ __forceinline__ void sm_merge(float& m, float& ss, int& a,
                                         float om, float os, int oa) {
    if (om > m || (om == m && oa < a)) {
        ss = os + ss * expf(m - om); m = om; a = oa;
    } else {
        ss += os * expf(om - m);
    }
}

__device__ __forceinline__ void st_agent_f(float* p, float v) {
    __hip_atomic_store(p, v, __ATOMIC_RELAXED, __HIP_MEMORY_SCOPE_AGENT);
}
__device__ __forceinline__ void st_agent_i(int* p, int v) {
    __hip_atomic_store(p, v, __ATOMIC_RELAXED, __HIP_MEMORY_SCOPE_AGENT);
}
__device__ __forceinline__ float ld_agent_f(const float* p) {
    return __hip_atomic_load(p, __ATOMIC_RELAXED, __HIP_MEMORY_SCOPE_AGENT);
}
__device__ __forceinline__ int ld_agent_i(const int* p) {
    return __hip_atomic_load(p, __ATOMIC_RELAXED, __HIP_MEMORY_SCOPE_AGENT);
}

// ---------------- init: h0 = enc, zero the per-step counters ----------------
__global__ void init_kernel(const float* __restrict__ enc, float* __restrict__ h0,
                            int* __restrict__ cnt) {
    for (int i = threadIdx.x; i < H; i += 256) h0[i] = enc[i];
    for (int i = threadIdx.x; i < STEPS; i += 256) cnt[i] = 0;
}

// ---------------- per-step GRU (scalar tok/logZ feedback) ----------------
__global__ __launch_bounds__(256) void gru_kernel(
    const float* __restrict__ emb, const float* __restrict__ W_ih,
    const float* __restrict__ W_hh, const float* __restrict__ b_ih,
    const float* __restrict__ b_hh, const float* __restrict__ h_cur,
    float* __restrict__ h_next, float* __restrict__ out_prev,
    const int* __restrict__ tok_p, const float* __restrict__ logz_p, int s) {
    const int tid = threadIdx.x;
    const int lane = tid & 63;
    const int wv = tid >> 6;
    const int b = blockIdx.x;
    const int i = b * 4 + wv;   // GRU output row (4 waves, one row each)

    // issue weight + h loads first; latency overlaps the scalar feedback read
    const float4* hp = (const float4*)h_cur;
    float4 hv[4];
    float4 WX0[4], WX1[4], WX2[4], WH0[4], WH1[4], WH2[4];
#pragma unroll
    for (int j = 0; j < 4; ++j) {
        const int idx = lane + 64 * j;
        hv[j] = hp[idx];
        WX0[j] = ((const float4*)(W_ih + (size_t)i * H))[idx];
        WX1[j] = ((const float4*)(W_ih + ((size_t)i + H) * H))[idx];
        WX2[j] = ((const float4*)(W_ih + ((size_t)i + 2 * H) * H))[idx];
        WH0[j] = ((const float4*)(W_hh + (size_t)i * H))[idx];
        WH1[j] = ((const float4*)(W_hh + ((size_t)i + H) * H))[idx];
        WH2[j] = ((const float4*)(W_hh + ((size_t)i + 2 * H) * H))[idx];
    }

    int tok = 0;
    if (s > 0) {
        tok = tok_p[0];
        const float lz = logz_p[0];
        if (tid < RPB1) out_prev[b * RPB1 + tid] -= lz;
    }

    const float4* xp = (const float4*)(emb + (size_t)tok * H);
    float4 xv[4];
#pragma unroll
    for (int j = 0; j < 4; ++j) xv[j] = xp[lane + 64 * j];

    float sx0 = 0, sx1 = 0, sx2 = 0, sh0 = 0, sh1 = 0, sh2 = 0;
#pragma unroll
    for (int j = 0; j < 4; ++j) {
        sx0 += dot4(WX0[j], xv[j]); sx1 += dot4(WX1[j], xv[j]); sx2 += dot4(WX2[j], xv[j]);
        sh0 += dot4(WH0[j], hv[j]); sh1 += dot4(WH1[j], hv[j]); sh2 += dot4(WH2[j], hv[j]);
    }
    sx0 = wave_sum(sx0); sx1 = wave_sum(sx1); sx2 = wave_sum(sx2);
    sh0 = wave_sum(sh0); sh1 = wave_sum(sh1); sh2 = wave_sum(sh2);
    if (lane == 0) {
        const float rg = 1.f / (1.f + expf(-((sx0 + b_ih[i]) + (sh0 + b_hh[i]))));
        const float zg = 1.f / (1.f + expf(-((sx1 + b_ih[i + H]) + (sh1 + b_hh[i + H]))));
        const float ng = tanhf((sx2 + b_ih[i + 2 * H]) + rg * (sh2 + b_hh[i + 2 * H]));
        h_next[i] = (1.f - zg) * ng + zg * h_cur[i];
    }
}

// ------- per-step logits GEMV + partials + LAST-BLOCK global argmax/logZ -------
__global__ __launch_bounds__(512, 2) void logits_kernel(
    const float* __restrict__ lin_W, const float* __restrict__ lin_b,
    const float* __restrict__ h_src, float* __restrict__ orow,
    float* __restrict__ pm, float* __restrict__ ps, int* __restrict__ pa,
    int* __restrict__ tok_out, float* __restrict__ logz_out,
    int* __restrict__ cnt) {
    const int tid = threadIdx.x;
    const int lane = tid & 63;
    const int wv = tid >> 6;
    const int b = blockIdx.x;
    const int row0 = (b < 256) ? 63 * b : 16128 + 62 * (b - 256);
    const int nrows = (b < 256) ? 63 : 62;

    __shared__ float red_m[8], red_s[8];
    __shared__ int red_a[8];
    __shared__ int s_last;

    const float4* h4 = (const float4*)h_src;
    float4 hr[4];
#pragma unroll
    for (int j = 0; j < 4; ++j) hr[j] = h4[lane + 64 * j];

    // ---- load ALL 8 rows' weights in one burst (32 dwordx4 = 512 B/lane) ----
    float4 w[8][4];
    bool val[8];
#pragma unroll
    for (int k = 0; k < 8; ++k) {
        const int rr = wv + 8 * k;
        val[k] = rr < nrows;
        const float4* p = (const float4*)(lin_W + (size_t)(row0 + (val[k] ? rr : 0)) * H);
#pragma unroll
        for (int j = 0; j < 4; ++j) w[k][j] = p[lane + 64 * j];
    }
    __builtin_amdgcn_sched_barrier(0);

    float m = -3.4e38f, ssum = 0.f;
    int arg = 0x7fffffff;
#pragma unroll
    for (int k = 0; k < 8; ++k) {
        float a = 0.f;
#pragma unroll
        for (int j = 0; j < 4; ++j) a += dot4(w[k][j], hr[j]);
        a = wave_sum(a);
        if (val[k]) {
            const int col = row0 + wv + 8 * k;
            a += lin_b[col];
            if (lane == 0) __builtin_nontemporal_store(a, &orow[col]);
            if (a > m) { ssum *= expf(m - a); m = a; arg = col; }
            ssum += expf(a - m);
        }
    }
    if (lane == 0) { red_m[wv] = m; red_s[wv] = ssum; red_a[wv] = arg; }
    __syncthreads();
    if (tid == 0) {
        float M = red_m[0], S = red_s[0];
        int A = red_a[0];
#pragma unroll
        for (int wq = 1; wq < 8; ++wq) sm_merge(M, S, A, red_m[wq], red_s[wq], red_a[wq]);
        st_agent_f(&pm[b], M);
        st_agent_f(&ps[b], S);
        st_agent_i(&pa[b], A);
        __builtin_amdgcn_fence(__ATOMIC_RELEASE, "agent");
        const int old = __hip_atomic_fetch_add(cnt, 1, __ATOMIC_ACQ_REL,
                                               __HIP_MEMORY_SCOPE_AGENT);
        s_last = (old == NB2 - 1);
    }
    __syncthreads();

    // ---- last finishing block: global reduce of 512 partials -> tok, logZ ----
    if (s_last) {
        __builtin_amdgcn_fence(__ATOMIC_ACQUIRE, "agent");
        float gm = ld_agent_f(&pm[tid]);
        float gs = ld_agent_f(&ps[tid]);
        int ga = ld_agent_i(&pa[tid]);
#pragma unroll
        for (int off = 32; off > 0; off >>= 1) {
            float om = __shfl_xor(gm, off), os = __shfl_xor(gs, off);
            int oa = __shfl_xor(ga, off);
            sm_merge(gm, gs, ga, om, os, oa);
        }
        if (lane == 0) { red_m[wv] = gm; red_s[wv] = gs; red_a[wv] = ga; }
        __syncthreads();
        if (tid == 0) {
            float M = red_m[0], S = red_s[0];
            int A = red_a[0];
#pragma unroll
            for (int wq = 1; wq < 8; ++wq) sm_merge(M, S, A, red_m[wq], red_s[wq], red_a[wq]);
            tok_out[0] = A;
            logz_out[0] = M + logf(S);
        }
    }
}

// ---------------- tail: finalize out[STEPS-1] + write h_final ----------------
__global__ __launch_bounds__(256) void tail_kernel(
    float* __restrict__ out_last, const float* __restrict__ logz_p,
    const float* __restrict__ h_final, float* __restrict__ out_h) {
    const int tid = threadIdx.x;
    const int b = blockIdx.x;
    const float logZ = logz_p[0];
    if (tid < RPB1) out_last[b * RPB1 + tid] -= logZ;
    if (b == 0)
        for (int i = tid; i < H; i += 256) out_h[i] = h_final[i];
}

extern "C" void kernel_launch(void* const* d_in, const int* in_sizes, int n_in,
                              void* d_out, int out_size, void* d_ws, size_t ws_size,
                              hipStream_t stream) {
    const float* enc = (const float*)d_in[0];
    const float* emb = (const float*)d_in[1];
    const float* W_ih = (const float*)d_in[2];
    const float* W_hh = (const float*)d_in[3];
    const float* b_ih = (const float*)d_in[4];
    const float* b_hh = (const float*)d_in[5];
    const float* lin_W = (const float*)d_in[6];
    const float* lin_b = (const float*)d_in[7];
    float* out = (float*)d_out;
    float* ws = (float*)d_ws;

    // ws: h_buf[2][H] | pm[NB2] | ps[NB2] | pa[NB2] | tok[STEPS] | logz[STEPS] | cnt[STEPS]
    float* h_buf = ws;
    float* pm = ws + 2 * H;
    float* ps = pm + NB2;
    int* pa = (int*)(ps + NB2);
    int* tok = pa + NB2;
    float* logz = (float*)(tok + STEPS);
    int* cnt = (int*)(logz + STEPS);

    init_kernel<<<1, 256, 0, stream>>>(enc, h_buf, cnt);
    for (int s = 0; s < STEPS; ++s) {
        float* h_cur = h_buf + (s & 1) * H;
        float* h_next = h_buf + ((s + 1) & 1) * H;
        float* out_prev = out + (size_t)(s > 0 ? s - 1 : 0) * V;
        const int sp = (s > 0) ? s - 1 : 0;
        gru_kernel<<<NB1, 256, 0, stream>>>(emb, W_ih, W_hh, b_ih, b_hh,
                                            h_cur, h_next, out_prev,
                                            tok + sp, logz + sp, s);
        logits_kernel<<<NB2, 512, 0, stream>>>(lin_W, lin_b, h_next,
                                               out + (size_t)s * V, pm, ps, pa,
                                               tok + s, logz + s, cnt + s);
    }
    tail_kernel<<<NB1, 256, 0, stream>>>(out + (size_t)(STEPS - 1) * V,
                                         logz + (STEPS - 1),
                                         h_buf + (STEPS & 1) * H,
                                         out + (size_t)V * STEPS);
}

// Round 13
// 15673.549 us; speedup vs baseline: 1.1168x; 1.1168x over previous
//
#include <hip/hip_runtime.h>

#define H 1024
#define V 32000
#define STEPS 375
#define NB1 256       // gru blocks
#define NB2 512       // logits blocks
#define RPB1 125      // out cols per gru block
#define DELTA 0.0625f // bf16->fp32 rescue margin (>=15x the 5.7-sigma bf16 dot error)

__device__ __forceinline__ float dot4(const float4 a, const float4 b) {
    return fmaf(a.x, b.x, fmaf(a.y, b.y, fmaf(a.z, b.z, a.w * b.w)));
}

__device__ __forceinline__ float wave_sum(float v) {
#pragma unroll
    for (int off = 32; off > 0; off >>= 1) v += __shfl_xor(v, off);
    return v;
}

__device__ __forceinline__ void sm_merge(float& m, float& ss, int& a,
                                         float om, float os, int oa) {
    if (om > m || (om == m && oa < a)) {
        ss = os + ss * expf(m - om); m = om; a = oa;
    } else {
        ss += os * expf(om - m);
    }
}

__device__ __forceinline__ float bl(unsigned u) { return __uint_as_float(u << 16); }
__device__ __forceinline__ float bh(unsigned u) { return __uint_as_float(u & 0xffff0000u); }

__device__ __forceinline__ unsigned f2bf(float f) {   // RNE fp32->bf16
    unsigned u = __float_as_uint(f);
    return (u + 0x7fffu + ((u >> 16) & 1u)) >> 16;
}

// ---------------- init: h0 = enc ----------------
__global__ void init_kernel(const float* __restrict__ enc, float* __restrict__ h0) {
    for (int i = threadIdx.x; i < H; i += 256) h0[i] = enc[i];
}

// ---------------- one-time: lin_W fp32 -> packed bf16 ----------------
__global__ __launch_bounds__(512) void conv_kernel(const float* __restrict__ src,
                                                   unsigned short* __restrict__ dst) {
    const size_t idx = (size_t)blockIdx.x * 512 + threadIdx.x;  // 4,096,000 total
    const float4* s4 = (const float4*)src;
    float4 a = s4[2 * idx], b = s4[2 * idx + 1];
    uint4 o;
    o.x = f2bf(a.x) | (f2bf(a.y) << 16);
    o.y = f2bf(a.z) | (f2bf(a.w) << 16);
    o.z = f2bf(b.x) | (f2bf(b.y) << 16);
    o.w = f2bf(b.z) | (f2bf(b.w) << 16);
    ((uint4*)dst)[idx] = o;
}

// ---------------- per-step GRU (r5 verbatim: argmax feedback + logZ RMW) ------
__global__ __launch_bounds__(256) void gru_kernel(
    const float* __restrict__ emb, const float* __restrict__ W_ih,
    const float* __restrict__ W_hh, const float* __restrict__ b_ih,
    const float* __restrict__ b_hh, const float* __restrict__ h_cur,
    float* __restrict__ h_next, float* __restrict__ out_prev,
    const float* __restrict__ pm, const float* __restrict__ ps,
    const int* __restrict__ pa, int s) {
    const int tid = threadIdx.x;
    const int lane = tid & 63;
    const int wv = tid >> 6;
    const int b = blockIdx.x;

    int tok = 0;
    if (s > 0) {
        float m = -3.4e38f, ss = 0.f;
        int a = 0x7fffffff;
#pragma unroll
        for (int k = 0; k < NB2 / 64; ++k)
            sm_merge(m, ss, a, pm[k * 64 + lane], ps[k * 64 + lane], pa[k * 64 + lane]);
#pragma unroll
        for (int off = 32; off > 0; off >>= 1) {
            float om = __shfl_xor(m, off), os = __shfl_xor(ss, off);
            int oa = __shfl_xor(a, off);
            sm_merge(m, ss, a, om, os, oa);
        }
        const float logZ = m + logf(ss);
        tok = a;
        if (tid < RPB1) out_prev[b * RPB1 + tid] -= logZ;
    }

    const int i = b * 4 + wv;   // GRU output row (4 waves, one row each)
    const float4* xp = (const float4*)(emb + (size_t)tok * H);
    const float4* hp = (const float4*)h_cur;
    float4 xv[4], hv[4];
#pragma unroll
    for (int j = 0; j < 4; ++j) {
        xv[j] = xp[lane + 64 * j];
        hv[j] = hp[lane + 64 * j];
    }
    const float4* wx0 = (const float4*)(W_ih + (size_t)i * H);
    const float4* wx1 = (const float4*)(W_ih + ((size_t)i + H) * H);
    const float4* wx2 = (const float4*)(W_ih + ((size_t)i + 2 * H) * H);
    const float4* wh0 = (const float4*)(W_hh + (size_t)i * H);
    const float4* wh1 = (const float4*)(W_hh + ((size_t)i + H) * H);
    const float4* wh2 = (const float4*)(W_hh + ((size_t)i + 2 * H) * H);
    float4 WX0[4], WX1[4], WX2[4], WH0[4], WH1[4], WH2[4];
#pragma unroll
    for (int j = 0; j < 4; ++j) {
        const int idx = lane + 64 * j;
        WX0[j] = wx0[idx]; WX1[j] = wx1[idx]; WX2[j] = wx2[idx];
        WH0[j] = wh0[idx]; WH1[j] = wh1[idx]; WH2[j] = wh2[idx];
    }
    float sx0 = 0, sx1 = 0, sx2 = 0, sh0 = 0, sh1 = 0, sh2 = 0;
#pragma unroll
    for (int j = 0; j < 4; ++j) {
        sx0 += dot4(WX0[j], xv[j]); sx1 += dot4(WX1[j], xv[j]); sx2 += dot4(WX2[j], xv[j]);
        sh0 += dot4(WH0[j], hv[j]); sh1 += dot4(WH1[j], hv[j]); sh2 += dot4(WH2[j], hv[j]);
    }
    sx0 = wave_sum(sx0); sx1 = wave_sum(sx1); sx2 = wave_sum(sx2);
    sh0 = wave_sum(sh0); sh1 = wave_sum(sh1); sh2 = wave_sum(sh2);
    if (lane == 0) {
        const float rg = 1.f / (1.f + expf(-((sx0 + b_ih[i]) + (sh0 + b_hh[i]))));
        const float zg = 1.f / (1.f + expf(-((sx1 + b_ih[i + H]) + (sh1 + b_hh[i + H]))));
        const float ng = tanhf((sx2 + b_ih[i + 2 * H]) + rg * (sh2 + b_hh[i + 2 * H]));
        h_next[i] = (1.f - zg) * ng + zg * h_cur[i];
    }
}

// ------ per-step logits: lean bf16 GEMV (r5 loop shape) + fp32 rescue ---------
// lane l owns contiguous elems [16l..16l+15]; hv[4] shared by bf16 dot AND rescue
__global__ __launch_bounds__(512, 4) void logits_bf16_kernel(
    const unsigned short* __restrict__ wbf, const float* __restrict__ lin_W,
    const float* __restrict__ lin_b, const float* __restrict__ h_src,
    float* __restrict__ orow, float* __restrict__ pm, float* __restrict__ ps,
    int* __restrict__ pa) {
    const int tid = threadIdx.x;
    const int lane = tid & 63;
    const int wv = tid >> 6;
    const int b = blockIdx.x;
    const int row0 = (b < 256) ? 63 * b : 16128 + 62 * (b - 256);
    const int nrows = (b < 256) ? 63 : 62;

    __shared__ float red_m[8], red_s[8];
    __shared__ float s_cm[8];
    __shared__ int s_ca[8];

    // h fragment: lane l covers elems 16l..16l+15 (contiguous, coalesced)
    const float4* h4 = (const float4*)h_src;
    float4 hv[4];
#pragma unroll
    for (int j = 0; j < 4; ++j) hv[j] = h4[4 * lane + j];

    float lg[8];
    float m = -3.4e38f, ssum = 0.f;

#pragma unroll
    for (int it = 0; it < 2; ++it) {
        // ---- 4-row batch: q[4][2] uint4 = 32 VGPR in flight ----
        uint4 q[4][2];
        bool val[4];
#pragma unroll
        for (int kq = 0; kq < 4; ++kq) {
            const int rr = wv + 8 * (4 * it + kq);
            val[kq] = rr < nrows;
            const uint4* wp = (const uint4*)(wbf + (size_t)(row0 + (val[kq] ? rr : 0)) * H);
            q[kq][0] = wp[2 * lane];
            q[kq][1] = wp[2 * lane + 1];
        }
        __builtin_amdgcn_sched_barrier(0);
#pragma unroll
        for (int kq = 0; kq < 4; ++kq) {
            const int slot = 4 * it + kq;
            float a = 0.f;
            a = fmaf(bl(q[kq][0].x), hv[0].x, a); a = fmaf(bh(q[kq][0].x), hv[0].y, a);
            a = fmaf(bl(q[kq][0].y), hv[0].z, a); a = fmaf(bh(q[kq][0].y), hv[0].w, a);
            a = fmaf(bl(q[kq][0].z), hv[1].x, a); a = fmaf(bh(q[kq][0].z), hv[1].y, a);
            a = fmaf(bl(q[kq][0].w), hv[1].z, a); a = fmaf(bh(q[kq][0].w), hv[1].w, a);
            a = fmaf(bl(q[kq][1].x), hv[2].x, a); a = fmaf(bh(q[kq][1].x), hv[2].y, a);
            a = fmaf(bl(q[kq][1].y), hv[2].z, a); a = fmaf(bh(q[kq][1].y), hv[2].w, a);
            a = fmaf(bl(q[kq][1].z), hv[3].x, a); a = fmaf(bh(q[kq][1].z), hv[3].y, a);
            a = fmaf(bl(q[kq][1].w), hv[3].z, a); a = fmaf(bh(q[kq][1].w), hv[3].w, a);
            a = wave_sum(a);
            if (val[kq]) {
                const int col = row0 + wv + 8 * slot;
                a += lin_b[col];
                lg[slot] = a;
                if (lane == 0) __builtin_nontemporal_store(a, &orow[col]);
                if (a > m) { ssum *= expf(m - a); m = a; }
                ssum += expf(a - m);
            } else {
                lg[slot] = -3.4e38f;
            }
        }
    }
    if (lane == 0) { red_m[wv] = m; red_s[wv] = ssum; }
    __syncthreads();

    // block bf16 max
    float Mb = red_m[0];
#pragma unroll
    for (int w = 1; w < 8; ++w) Mb = fmaxf(Mb, red_m[w]);

    // fp32 rescue of candidate rows (wave-uniform predicate; ~0-2 per block)
    float cm = -3.4e38f;
    int ca = 0x7fffffff;
#pragma unroll
    for (int k = 0; k < 8; ++k) {
        if (lg[k] > Mb - DELTA) {
            const int row = row0 + wv + 8 * k;
            const float4* rp = (const float4*)(lin_W + (size_t)row * H);
            float a = 0.f;
#pragma unroll
            for (int j = 0; j < 4; ++j) a += dot4(rp[4 * lane + j], hv[j]);
            a = wave_sum(a) + lin_b[row];
            if (a > cm || (a == cm && row < ca)) { cm = a; ca = row; }
        }
    }
    if (lane == 0) { s_cm[wv] = cm; s_ca[wv] = ca; }
    __syncthreads();
    if (tid == 0) {
        float M = red_m[0], S = red_s[0];
#pragma unroll
        for (int w = 1; w < 8; ++w) {   // merge sums (max-only component)
            const float mw = red_m[w], sw = red_s[w];
            if (mw > M) { S = sw + S * expf(M - mw); M = mw; }
            else S += sw * expf(mw - M);
        }
        float CM = s_cm[0];
        int CA = s_ca[0];
#pragma unroll
        for (int w = 1; w < 8; ++w)
            if (s_cm[w] > CM || (s_cm[w] == CM && s_ca[w] < CA)) { CM = s_cm[w]; CA = s_ca[w]; }
        pm[b] = CM;                    // fp32-exact block max (argmax-safe)
        ps[b] = S * expf(M - CM);      // bf16 sumexp re-anchored to CM
        pa[b] = CA;
    }
}

// ---------------- fallback fp32 logits (r5 verbatim) ----------------
__global__ __launch_bounds__(512, 4) void logits_fp32_kernel(
    const float* __restrict__ lin_W, const float* __restrict__ lin_b,
    const float* __restrict__ h_src, float* __restrict__ orow,
    float* __restrict__ pm, float* __restrict__ ps, int* __restrict__ pa) {
    const int tid = threadIdx.x;
    const int lane = tid & 63;
    const int wv = tid >> 6;
    const int b = blockIdx.x;
    const int row0 = (b < 256) ? 63 * b : 16128 + 62 * (b - 256);
    const int nrows = (b < 256) ? 63 : 62;

    __shared__ float red_m[8], red_s[8];
    __shared__ int red_a[8];

    const float4* h4 = (const float4*)h_src;
    float4 hr[4];
#pragma unroll
    for (int j = 0; j < 4; ++j) hr[j] = h4[lane + 64 * j];

    float m = -3.4e38f, ssum = 0.f;
    int arg = 0x7fffffff;
    for (int r = wv; r < nrows; r += 32) {
        const int rB = r + 8, rC = r + 16, rD = r + 24;
        const bool vB = rB < nrows, vC = rC < nrows, vD = rD < nrows;
        float4 wA[4], wB[4], wC[4], wD[4];
#pragma unroll
        for (int j = 0; j < 4; ++j) {
            const int idx = lane + 64 * j;
            wA[j] = ((const float4*)(lin_W + (size_t)(row0 + r) * H))[idx];
            wB[j] = ((const float4*)(lin_W + (size_t)(row0 + (vB ? rB : r)) * H))[idx];
            wC[j] = ((const float4*)(lin_W + (size_t)(row0 + (vC ? rC : r)) * H))[idx];
            wD[j] = ((const float4*)(lin_W + (size_t)(row0 + (vD ? rD : r)) * H))[idx];
        }
        __builtin_amdgcn_sched_barrier(0);
        float aA = 0, aB = 0, aC = 0, aD = 0;
#pragma unroll
        for (int j = 0; j < 4; ++j) {
            aA += dot4(wA[j], hr[j]); aB += dot4(wB[j], hr[j]);
            aC += dot4(wC[j], hr[j]); aD += dot4(wD[j], hr[j]);
        }
        aA = wave_sum(aA); aB = wave_sum(aB);
        aC = wave_sum(aC); aD = wave_sum(aD);
        aA += lin_b[row0 + r];
        if (lane == 0) __builtin_nontemporal_store(aA, &orow[row0 + r]);
        if (aA > m) { ssum *= expf(m - aA); m = aA; arg = row0 + r; }
        ssum += expf(aA - m);
        if (vB) {
            aB += lin_b[row0 + rB];
            if (lane == 0) __builtin_nontemporal_store(aB, &orow[row0 + rB]);
            if (aB > m) { ssum *= expf(m - aB); m = aB; arg = row0 + rB; }
            ssum += expf(aB - m);
        }
        if (vC) {
            aC += lin_b[row0 + rC];
            if (lane == 0) __builtin_nontemporal_store(aC, &orow[row0 + rC]);
            if (aC > m) { ssum *= expf(m - aC); m = aC; arg = row0 + rC; }
            ssum += expf(aC - m);
        }
        if (vD) {
            aD += lin_b[row0 + rD];
            if (lane == 0) __builtin_nontemporal_store(aD, &orow[row0 + rD]);
            if (aD > m) { ssum *= expf(m - aD); m = aD; arg = row0 + rD; }
            ssum += expf(aD - m);
        }
    }
    if (lane == 0) { red_m[wv] = m; red_s[wv] = ssum; red_a[wv] = arg; }
    __syncthreads();
    if (tid == 0) {
        float M = red_m[0], S = red_s[0];
        int A = red_a[0];
#pragma unroll
        for (int w = 1; w < 8; ++w) sm_merge(M, S, A, red_m[w], red_s[w], red_a[w]);
        pm[b] = M; ps[b] = S; pa[b] = A;
    }
}

// ---------------- tail: finalize out[STEPS-1] + write h_final ----------------
__global__ __launch_bounds__(256) void tail_kernel(
    float* __restrict__ out_last, const float* __restrict__ pm,
    const float* __restrict__ ps, const int* __restrict__ pa,
    const float* __restrict__ h_final, float* __restrict__ out_h) {
    const int tid = threadIdx.x;
    const int lane = tid & 63;
    const int b = blockIdx.x;
    float m = -3.4e38f, ss = 0.f;
    int a = 0x7fffffff;
#pragma unroll
    for (int k = 0; k < NB2 / 64; ++k)
        sm_merge(m, ss, a, pm[k * 64 + lane], ps[k * 64 + lane], pa[k * 64 + lane]);
#pragma unroll
    for (int off = 32; off > 0; off >>= 1) {
        float om = __shfl_xor(m, off), os = __shfl_xor(ss, off);
        int oa = __shfl_xor(a, off);
        sm_merge(m, ss, a, om, os, oa);
    }
    const float logZ = m + logf(ss);
    if (tid < RPB1) out_last[b * RPB1 + tid] -= logZ;
    if (b == 0)
        for (int i = tid; i < H; i += 256) out_h[i] = h_final[i];
}

extern "C" void kernel_launch(void* const* d_in, const int* in_sizes, int n_in,
                              void* d_out, int out_size, void* d_ws, size_t ws_size,
                              hipStream_t stream) {
    const float* enc = (const float*)d_in[0];
    const float* emb = (const float*)d_in[1];
    const float* W_ih = (const float*)d_in[2];
    const float* W_hh = (const float*)d_in[3];
    const float* b_ih = (const float*)d_in[4];
    const float* b_hh = (const float*)d_in[5];
    const float* lin_W = (const float*)d_in[6];
    const float* lin_b = (const float*)d_in[7];
    float* out = (float*)d_out;
    float* ws = (float*)d_ws;

    // ws: h_buf[2][H] | pm[NB2] | ps[NB2] | pa[NB2](int) | pad-to-16KB | wbf
    float* h_buf = ws;
    float* pm = ws + 2 * H;
    float* ps = pm + NB2;
    int* pa = (int*)(ps + NB2);
    unsigned short* wbf = (unsigned short*)((char*)d_ws + 16384);
    const size_t need = 16384 + (size_t)V * H * 2;
    const bool bf16path = ws_size >= need;

    init_kernel<<<1, 256, 0, stream>>>(enc, h_buf);
    if (bf16path)
        conv_kernel<<<V * H / 8 / 512, 512, 0, stream>>>(lin_W, wbf);
    for (int s = 0; s < STEPS; ++s) {
        float* h_cur = h_buf + (s & 1) * H;
        float* h_next = h_buf + ((s + 1) & 1) * H;
        float* out_prev = out + (size_t)(s > 0 ? s - 1 : 0) * V;
        gru_kernel<<<NB1, 256, 0, stream>>>(emb, W_ih, W_hh, b_ih, b_hh,
                                            h_cur, h_next, out_prev,
                                            pm, ps, pa, s);
        if (bf16path)
            logits_bf16_kernel<<<NB2, 512, 0, stream>>>(wbf, lin_W, lin_b, h_next,
                                                        out + (size_t)s * V, pm, ps, pa);
        else
            logits_fp32_kernel<<<NB2, 512, 0, stream>>>(lin_W, lin_b, h_next,
                                                        out + (size_t)s * V, pm, ps, pa);
    }
    tail_kernel<<<NB1, 256, 0, stream>>>(out + (size_t)(STEPS - 1) * V, pm, ps, pa,
                                         h_buf + (STEPS & 1) * H,
                                         out + (size_t)V * STEPS);
}